// Round 11
// baseline (209.960 us; speedup 1.0000x reference)
//
#include <hip/hip_runtime.h>
#include <cfloat>
#include <climits>

#define NB 16
#define NC 32
#define NZ 48
#define NY 48
#define YZ 2304             // NY*NZ
#define XYZ 110592          // 48^3
#define SUM_NUM 56623104.0  // 16*32*110592
#define SPS 216             // 512-voxel stripes per sample (XYZ/512)
#define NST (NB*SPS)        // 3456 wave-units
#define GRID (NST/4)        // 864 blocks x 4 waves

struct Ws {
  float p0[NST*NC];   // per (stripe, channel): sum sq
  float px[NST*NC];   //                        sum sq*x
  float py[NST*NC];   //                        sum sq*y
  float pm[NST*NC];   //                        channel max value
  int   pi[NST*NC];   //                        argmax voxel (sample-local)
  float pd[NST][4];   // per stripe: A, B, vsum, q2
};

#define TOP2(m1, m2, x) do { \
    if ((x) > (m1)) { (m2) = (m1); (m1) = (x); } \
    else if ((x) > (m2)) (m2) = (x); \
  } while (0)

// Single pass, ZERO barriers. Wave = 512-voxel stripe; lane owns 8 voxels
// (two float4). Per channel: 2 coalesced loads -> per-voxel top-2/qs stay
// per-lane -> butterfly shfl_xor reduces {s0,sx,sy} (per-lane x,y weights)
// and {max,idx}; lane c retains channel c's results in registers.
__global__ __launch_bounds__(256) void k_main(const float* __restrict__ f,
                                              Ws* __restrict__ ws) {
  const int t  = threadIdx.x;
  const int l  = t & 63;
  const int wv = blockIdx.x * 4 + (t >> 6);   // stripe id, 0..3455
  const int b  = wv / SPS;
  const int sl = wv - b * SPS;
  const int g0 = sl * 512;                    // stripe base voxel (sample-local)
  const int ga = g0 + 4 * l;                  // group-a f4 (never crosses a row: 4|48)
  const int gb = g0 + 256 + 4 * l;            // group-b f4

  const float xa = (float)(ga / YZ), ya = (float)((ga / NZ) % NY);
  const float xb = (float)(gb / YZ), yb = (float)((gb / NZ) % NY);
  const float r2a = xa * xa + ya * ya, r2b = xb * xb + yb * yb;

  const float* __restrict__ pa = f + (size_t)b * NC * XYZ + ga;
  const float* __restrict__ pbp = f + (size_t)b * NC * XYZ + gb;

  // per-voxel-slot div state (8 voxels/lane)
  float m1[8], m2[8], qs[8];
#pragma unroll
  for (int e = 0; e < 8; ++e) { m1[e] = -FLT_MAX; m2[e] = -FLT_MAX; qs[e] = 0.f; }
  float vsum = 0.f, q2a = 0.f;
  // lane c's retained channel-c results
  float rs0 = 0.f, rsx = 0.f, rsy = 0.f, rmx = 0.f;
  int   rmi = 0;

#pragma unroll 8
  for (int c = 0; c < NC; ++c) {
    const float4 va = *reinterpret_cast<const float4*>(pa + (size_t)c * XYZ);
    const float4 vb = *reinterpret_cast<const float4*>(pbp + (size_t)c * XYZ);

    const float qa0 = va.x*va.x, qa1 = va.y*va.y, qa2 = va.z*va.z, qa3 = va.w*va.w;
    const float qb0 = vb.x*vb.x, qb1 = vb.y*vb.y, qb2 = vb.z*vb.z, qb3 = vb.w*vb.w;
    qs[0] += qa0; qs[1] += qa1; qs[2] += qa2; qs[3] += qa3;
    qs[4] += qb0; qs[5] += qb1; qs[6] += qb2; qs[7] += qb3;
    const float sa = (qa0 + qa1) + (qa2 + qa3);
    const float sb = (qb0 + qb1) + (qb2 + qb3);
    vsum += ((va.x + va.y) + (va.z + va.w)) + ((vb.x + vb.y) + (vb.z + vb.w));
    q2a = fmaf(sa, r2a, q2a); q2a = fmaf(sb, r2b, q2a);

    float s0 = sa + sb;
    float sx = sa * xa + sb * xb;
    float sy = sa * ya + sb * yb;

    // lane-local channel max, ascending voxel order (strict '>': first wins)
    float mm = va.x; int jj = ga;
    if (va.y > mm) { mm = va.y; jj = ga + 1; }
    if (va.z > mm) { mm = va.z; jj = ga + 2; }
    if (va.w > mm) { mm = va.w; jj = ga + 3; }
    if (vb.x > mm) { mm = vb.x; jj = gb;     }
    if (vb.y > mm) { mm = vb.y; jj = gb + 1; }
    if (vb.z > mm) { mm = vb.z; jj = gb + 2; }
    if (vb.w > mm) { mm = vb.w; jj = gb + 3; }

    // butterfly reduces: all lanes end with wave totals
#pragma unroll
    for (int m_ = 1; m_ < 64; m_ <<= 1) {
      s0 += __shfl_xor(s0, m_);
      sx += __shfl_xor(sx, m_);
      sy += __shfl_xor(sy, m_);
    }
#pragma unroll
    for (int m_ = 1; m_ < 64; m_ <<= 1) {
      const float ov = __shfl_xor(mm, m_);
      const int   oi = __shfl_xor(jj, m_);
      if (ov > mm || (ov == mm && oi < jj)) { mm = ov; jj = oi; }
    }
    if (l == c) { rs0 = s0; rsx = sx; rsy = sy; rmx = mm; rmi = jj; }

    // per-voxel top-2 over channels
    TOP2(m1[0], m2[0], va.x); TOP2(m1[1], m2[1], va.y);
    TOP2(m1[2], m2[2], va.z); TOP2(m1[3], m2[3], va.w);
    TOP2(m1[4], m2[4], vb.x); TOP2(m1[5], m2[5], vb.y);
    TOP2(m1[6], m2[6], vb.z); TOP2(m1[7], m2[7], vb.w);
  }

  // div moments from per-voxel top-2 (exclude-self trick)
  float A = 0.f, Bv = 0.f;
#pragma unroll
  for (int e = 0; e < 8; ++e) {
    const float q = m1[e] * m1[e], rest = qs[e] - q;
    A  += q * rest + m2[e] * m2[e] * q;
    Bv += m1[e] * rest + m2[e] * q;
  }
#pragma unroll
  for (int m_ = 1; m_ < 64; m_ <<= 1) {
    A    += __shfl_xor(A,    m_);
    Bv   += __shfl_xor(Bv,   m_);
    vsum += __shfl_xor(vsum, m_);
    q2a  += __shfl_xor(q2a,  m_);
  }

  // coalesced per-channel partial writes (lanes 0..31 = channels)
  if (l < NC) {
    const int o = wv * NC + l;
    ws->p0[o] = rs0; ws->px[o] = rsx; ws->py[o] = rsy;
    ws->pm[o] = rmx; ws->pi[o] = rmi;
  }
  if (l == 0) {
    ws->pd[wv][0] = A; ws->pd[wv][1] = Bv;
    ws->pd[wv][2] = vsum; ws->pd[wv][3] = q2a;
  }
}

// ---- finalize: thread = (b,c); merge 216 stripe partials; assemble in f64 ----
__global__ __launch_bounds__(512) void k_fin(const Ws* __restrict__ ws,
                                             float* __restrict__ out) {
  const int t = threadIdx.x;
  const int b = t >> 5, c = t & 31;
  double s0 = 0, sx = 0, sy = 0;
  float mv = -FLT_MAX; int mi = INT_MAX;
  for (int k = 0; k < SPS; ++k) {              // ascending stripe keeps first
    const int o = (b * SPS + k) * NC + c;
    s0 += ws->p0[o]; sx += ws->px[o]; sy += ws->py[o];
    const float ov = ws->pm[o]; const int oi = ws->pi[o];
    if (ov > mv || (ov == mv && oi < mi)) { mv = ov; mi = oi; }
  }
  const double mx = (double)(mi / YZ);
  const double my = (double)((mi / NZ) % NY);
  const double mz = (double)(mi % NZ);
  double dis = (mx*mx + my*my) * s0 - 2.0*mx*sx - 2.0*my*sy
             + 2304.0 * (48.0*mz*mz - 2256.0*mz + 35720.0);
  double s0t = s0, a = 0.0, bb2 = 0.0, vsm = 0.0, q2 = 0.0;
  for (int i = t; i < NST; i += 512) {
    a += ws->pd[i][0]; bb2 += ws->pd[i][1];
    vsm += ws->pd[i][2]; q2 += ws->pd[i][3];
  }
  for (int off = 32; off > 0; off >>= 1) {
    dis += __shfl_down(dis, off);
    s0t += __shfl_down(s0t, off);
    a   += __shfl_down(a,   off);
    bb2 += __shfl_down(bb2, off);
    vsm += __shfl_down(vsm, off);
    q2  += __shfl_down(q2,  off);
  }
  __shared__ double sd[8][6];
  const int wid = t >> 6;
  if ((t & 63) == 0) {
    sd[wid][0]=dis; sd[wid][1]=s0t; sd[wid][2]=a;
    sd[wid][3]=bb2; sd[wid][4]=vsm; sd[wid][5]=q2;
  }
  __syncthreads();
  if (t == 0) {
    for (int q = 1; q < 8; ++q) {
      dis += sd[q][0]; s0t += sd[q][1]; a += sd[q][2];
      bb2 += sd[q][3]; vsm += sd[q][4]; q2 += sd[q][5];
    }
    const double mgr = vsm / SUM_NUM;
    out[0] = (float)((dis + q2) / SUM_NUM);
    out[1] = (float)((a - 2.0*mgr*bb2 + mgr*mgr*s0t) / SUM_NUM);
  }
}

extern "C" void kernel_launch(void* const* d_in, const int* in_sizes, int n_in,
                              void* d_out, int out_size, void* d_ws, size_t ws_size,
                              hipStream_t stream) {
  const float* f = (const float*)d_in[0];
  Ws* ws = (Ws*)d_ws;
  float* out = (float*)d_out;
  hipLaunchKernelGGL(k_main, dim3(GRID), dim3(256), 0, stream, f, ws);
  hipLaunchKernelGGL(k_fin,  dim3(1),    dim3(512), 0, stream, ws, out);
}

// Round 12
// 96.166 us; speedup vs baseline: 2.1833x; 2.1833x over previous
//
#include <hip/hip_runtime.h>
#include <cfloat>
#include <climits>

#define NB 16
#define NC 32
#define NZ 48
#define NY 48
#define YZ 2304             // NY*NZ
#define XYZ 110592          // 48^3
#define SUM_NUM 56623104.0  // 16*32*110592
#define TPB 256
#define VPB 1024            // voxels per block (4 waves x 256-voxel stripes)
#define PBS 108             // blocks per sample
#define GRID (NB*PBS)       // 1728

struct BP {
  float s0[NC], sx[NC], sy[NC], mx[NC];
  int   mi[NC];
  float A, B, vs, q2;
};
struct Ws { BP bp[GRID]; };

#define TOP2(m1, m2, x) do { \
    if ((x) > (m1)) { (m2) = (m1); (m1) = (x); } \
    else if ((x) > (m2)) (m2) = (x); \
  } while (0)

// ---- DPP wave64 reductions on the VALU pipe (rocPRIM pattern) ----
// row_shr:1/2/4/8 then row_bcast15/31; total lands in lane 63.
template <int CTRL>
__device__ __forceinline__ float dppadd(float s) {
  return s + __int_as_float(__builtin_amdgcn_update_dpp(
      0, __float_as_int(s), CTRL, 0xF, 0xF, false));
}
template <int CTRL>
__device__ __forceinline__ float dppmax(float m) {
  const int mb = __float_as_int(m);
  return fmaxf(m, __int_as_float(__builtin_amdgcn_update_dpp(
      mb, mb, CTRL, 0xF, 0xF, false)));  // old=self: invalid lanes keep m
}
__device__ __forceinline__ float wave_sum63(float s) {
  s = dppadd<0x111>(s); s = dppadd<0x112>(s);
  s = dppadd<0x114>(s); s = dppadd<0x118>(s);
  s = dppadd<0x142>(s); s = dppadd<0x143>(s);
  return s;
}
__device__ __forceinline__ float wave_max63(float m) {
  m = dppmax<0x111>(m); m = dppmax<0x112>(m);
  m = dppmax<0x114>(m); m = dppmax<0x118>(m);
  m = dppmax<0x142>(m); m = dppmax<0x143>(m);
  return m;
}

// Single pass, no in-loop barriers, no DS shuffles, no per-channel register
// arrays. Wave = 256-voxel stripe (x wave-constant); per channel: load f4 ->
// per-voxel top-2/qs (lane-local) -> DPP-reduce {s, s*y} and max -> ballot
// argmax -> lane 0 writes the wave's {s0, sy, max, idx} slot to LDS.
__global__ __launch_bounds__(256) void k_main(const float* __restrict__ f,
                                              Ws* __restrict__ ws) {
  const int bb = blockIdx.x / PBS;
  const int pb = blockIdx.x - bb * PBS;
  const int t  = threadIdx.x;
  const int w  = t >> 6, l = t & 63;
  const int g  = pb * VPB + w * 256 + 4 * l;  // lane's 4 voxels (sample-local)
  const float* __restrict__ p = f + (size_t)bb * NC * XYZ + g;

  const float yf = (float)((g / NZ) % NY);    // lane-constant (4 | 48)
  const float xf = (float)(g / YZ);           // wave-constant (256 | 2304)
  const float r2 = xf * xf + yf * yf;

  __shared__ float4 slot[4][NC];              // per-wave {s0, sy, max, idx}
  __shared__ float rr[4][4];

  float m1[4], m2[4], qs[4];
#pragma unroll
  for (int e = 0; e < 4; ++e) { m1[e] = -FLT_MAX; m2[e] = -FLT_MAX; qs[e] = 0.f; }
  float vsum = 0.f, q2a = 0.f;

#pragma unroll 4
  for (int c = 0; c < NC; ++c) {
    const float4 v = *reinterpret_cast<const float4*>(p + (size_t)c * XYZ);
    const float q0 = v.x*v.x, q1 = v.y*v.y, q2v = v.z*v.z, q3 = v.w*v.w;
    qs[0] += q0; qs[1] += q1; qs[2] += q2v; qs[3] += q3;
    vsum += (v.x + v.y) + (v.z + v.w);
    const float s = (q0 + q1) + (q2v + q3);
    q2a = fmaf(s, r2, q2a);

    float mm = v.x; int jj = g;                // strict '>': first index wins
    if (v.y > mm) { mm = v.y; jj = g + 1; }
    if (v.z > mm) { mm = v.z; jj = g + 2; }
    if (v.w > mm) { mm = v.w; jj = g + 3; }

    TOP2(m1[0], m2[0], v.x);
    TOP2(m1[1], m2[1], v.y);
    TOP2(m1[2], m2[2], v.z);
    TOP2(m1[3], m2[3], v.w);

    const float s0t = wave_sum63(s);
    const float syt = wave_sum63(s * yf);
    const float mxt = wave_max63(mm);
    const int mxb = __builtin_amdgcn_readlane(__float_as_int(mxt), 63);
    const unsigned long long msk = __ballot(__float_as_int(mm) == mxb);
    const int fl = __ffsll((unsigned long long)msk) - 1;   // lowest lane = first voxel
    const int jwin = __builtin_amdgcn_readlane(jj, fl);
    const int s0b = __builtin_amdgcn_readlane(__float_as_int(s0t), 63);
    const int syb = __builtin_amdgcn_readlane(__float_as_int(syt), 63);
    if (l == 0)
      slot[w][c] = make_float4(__int_as_float(s0b), __int_as_float(syb),
                               __int_as_float(mxb), __int_as_float(jwin));
  }

  // per-voxel div moments (exclude-self top-2 trick)
  float A = 0.f, Bv = 0.f;
#pragma unroll
  for (int e = 0; e < 4; ++e) {
    const float q = m1[e] * m1[e], rest = qs[e] - q;
    A  += q * rest + m2[e] * m2[e] * q;
    Bv += m1[e] * rest + m2[e] * q;
  }
  A = wave_sum63(A); Bv = wave_sum63(Bv);
  vsum = wave_sum63(vsum); q2a = wave_sum63(q2a);
  if (l == 63) { rr[w][0] = A; rr[w][1] = Bv; rr[w][2] = vsum; rr[w][3] = q2a; }
  __syncthreads();                            // the ONLY barrier

  BP* bp = &ws->bp[blockIdx.x];
  if (t < NC) {
    float bs0 = 0.f, bsx = 0.f, bsy = 0.f, bm = -FLT_MAX; int bj = 0;
#pragma unroll
    for (int w2 = 0; w2 < 4; ++w2) {          // ascending wave = ascending voxel
      const float4 sl = slot[w2][t];
      const float xw = (float)((pb * VPB + w2 * 256) / YZ);
      bs0 += sl.x;
      bsx  = fmaf(xw, sl.x, bsx);
      bsy += sl.y;
      if (sl.z > bm) { bm = sl.z; bj = __float_as_int(sl.w); }
    }
    bp->s0[t] = bs0; bp->sx[t] = bsx; bp->sy[t] = bsy;
    bp->mx[t] = bm;  bp->mi[t] = bj;
  }
  if (t == 0) {
    bp->A  = (rr[0][0]+rr[1][0]) + (rr[2][0]+rr[3][0]);
    bp->B  = (rr[0][1]+rr[1][1]) + (rr[2][1]+rr[3][1]);
    bp->vs = (rr[0][2]+rr[1][2]) + (rr[2][2]+rr[3][2]);
    bp->q2 = (rr[0][3]+rr[1][3]) + (rr[2][3]+rr[3][3]);
  }
}

// ---- finalize (verified rounds 5/10): merge 108 partials per (b,c), f64 ----
__global__ __launch_bounds__(512) void k_fin(const Ws* __restrict__ ws,
                                             float* __restrict__ out) {
  const int t = threadIdx.x;
  const int b = t >> 5, c = t & 31;
  double s0 = 0, sx = 0, sy = 0;
  float mv = -FLT_MAX; int mi = INT_MAX;
  for (int k = 0; k < PBS; ++k) {
    const BP* p = &ws->bp[b * PBS + k];
    s0 += p->s0[c]; sx += p->sx[c]; sy += p->sy[c];
    const float ov = p->mx[c]; const int oi = p->mi[c];
    if (ov > mv || (ov == mv && oi < mi)) { mv = ov; mi = oi; }
  }
  const double mx = (double)(mi / YZ);
  const double my = (double)((mi / NZ) % NY);
  const double mz = (double)(mi % NZ);
  double dis = (mx*mx + my*my) * s0 - 2.0*mx*sx - 2.0*my*sy
             + 2304.0 * (48.0*mz*mz - 2256.0*mz + 35720.0);
  double s0t = s0, a = 0.0, bb2 = 0.0, vsm = 0.0, q2 = 0.0;
  for (int i = t; i < GRID; i += 512) {
    a += ws->bp[i].A; bb2 += ws->bp[i].B; vsm += ws->bp[i].vs; q2 += ws->bp[i].q2;
  }
  for (int off = 32; off > 0; off >>= 1) {
    dis += __shfl_down(dis, off);
    s0t += __shfl_down(s0t, off);
    a   += __shfl_down(a,   off);
    bb2 += __shfl_down(bb2, off);
    vsm += __shfl_down(vsm, off);
    q2  += __shfl_down(q2,  off);
  }
  __shared__ double sd[8][6];
  const int wid = t >> 6;
  if ((t & 63) == 0) {
    sd[wid][0]=dis; sd[wid][1]=s0t; sd[wid][2]=a;
    sd[wid][3]=bb2; sd[wid][4]=vsm; sd[wid][5]=q2;
  }
  __syncthreads();
  if (t == 0) {
    for (int q = 1; q < 8; ++q) {
      dis += sd[q][0]; s0t += sd[q][1]; a += sd[q][2];
      bb2 += sd[q][3]; vsm += sd[q][4]; q2 += sd[q][5];
    }
    const double mgr = vsm / SUM_NUM;
    out[0] = (float)((dis + q2) / SUM_NUM);
    out[1] = (float)((a - 2.0*mgr*bb2 + mgr*mgr*s0t) / SUM_NUM);
  }
}

extern "C" void kernel_launch(void* const* d_in, const int* in_sizes, int n_in,
                              void* d_out, int out_size, void* d_ws, size_t ws_size,
                              hipStream_t stream) {
  const float* f = (const float*)d_in[0];
  Ws* ws = (Ws*)d_ws;
  float* out = (float*)d_out;
  hipLaunchKernelGGL(k_main, dim3(GRID), dim3(TPB), 0, stream, f, ws);
  hipLaunchKernelGGL(k_fin,  dim3(1),    dim3(512), 0, stream, ws, out);
}

// Round 13
// 74.906 us; speedup vs baseline: 2.8030x; 1.2838x over previous
//
#include <hip/hip_runtime.h>
#include <cfloat>
#include <climits>

#define NB 16
#define NC 32
#define NBC (NB*NC)         // 512
#define NZ 48
#define NY 48
#define YZ 2304             // NY*NZ
#define XYZ 110592          // 48^3
#define Q (XYZ/4)           // 27648 float4 per (b,c)
#define SUM_NUM 56623104.0  // 16*32*110592
#define NBLK_B 108          // B-role blocks per sample (108*256*4 voxels)
#define K2_BLOCKS (NB*NBLK_B)
#define RPS 140             // roles per sample: 32 A + 108 B
#define GRID (NB*RPS)       // 2240

struct Ws {
  int   amax[NBC];
  float vsum[NBC], S0[NBC], Sx[NBC], Sy[NBC], Sq2[NBC];
  float pA[K2_BLOCKS], pB[K2_BLOCKS];
};

#define TOP2(m1, m2, x) do { \
    if ((x) > (m1)) { (m2) = (m1); (m1) = (x); } \
    else if ((x) > (m2)) (m2) = (x); \
  } while (0)

// One dispatch, two block roles, interleaved per sample so role-A's HBM
// fetches are L2/L3-hits for role-B (and vice versa). Proportional
// interleave: role A iff floor(32(r+1)/140) > floor(32r/140).
__global__ __launch_bounds__(256) void k_all(const float* __restrict__ f,
                                             Ws* __restrict__ ws) {
  const int b = blockIdx.x / RPS;
  const int r = blockIdx.x - b * RPS;
  const int t = threadIdx.x;
  const int w = t >> 6, l = t & 63;
  const int fA  = (32 * r) / RPS;
  const int fA1 = (32 * (r + 1)) / RPS;

  if (fA1 > fA) {
    // ================= role A: per-(b,c) moments + argmax =================
    const int bc = b * NC + fA;
    const float4* __restrict__ p = reinterpret_cast<const float4*>(f + (size_t)bc * XYZ);
    float bmax = -FLT_MAX; int bidx = 0;
    float vs = 0.f, s0 = 0.f, sx = 0.f, sy = 0.f, sq2 = 0.f;
#pragma unroll 4
    for (int i = t; i < Q; i += 256) {
      const float4 v = p[i];
      const int base = i << 2;
      const float xf = (float)(i / 576);          // 576 f4 per x-slab
      const float yf = (float)((i / 12) % 48);    // 12 f4 per y-row
      const float sq = (v.x*v.x + v.y*v.y) + (v.z*v.z + v.w*v.w);
      vs += (v.x + v.y) + (v.z + v.w);
      s0 += sq;
      sx  = fmaf(sq, xf, sx);
      sy  = fmaf(sq, yf, sy);
      sq2 = fmaf(sq, fmaf(xf, xf, yf*yf), sq2);
      float m = v.x; int e = 0;                   // strict '>': first index
      if (v.y > m) { m = v.y; e = 1; }
      if (v.z > m) { m = v.z; e = 2; }
      if (v.w > m) { m = v.w; e = 3; }
      if (m > bmax) { bmax = m; bidx = base + e; }
    }
    for (int off = 32; off > 0; off >>= 1) {
      vs  += __shfl_down(vs,  off);
      s0  += __shfl_down(s0,  off);
      sx  += __shfl_down(sx,  off);
      sy  += __shfl_down(sy,  off);
      sq2 += __shfl_down(sq2, off);
      const float ov = __shfl_down(bmax, off);
      const int   oi = __shfl_down(bidx, off);
      if (ov > bmax || (ov == bmax && oi < bidx)) { bmax = ov; bidx = oi; }
    }
    __shared__ float svs[4], ss0[4], ssx[4], ssy[4], ssq2[4], smx[4];
    __shared__ int   sbi[4];
    if (l == 0) { svs[w]=vs; ss0[w]=s0; ssx[w]=sx; ssy[w]=sy; ssq2[w]=sq2;
                  smx[w]=bmax; sbi[w]=bidx; }
    __syncthreads();
    if (t == 0) {
      for (int q = 1; q < 4; ++q) {
        vs += svs[q]; s0 += ss0[q]; sx += ssx[q]; sy += ssy[q]; sq2 += ssq2[q];
        if (smx[q] > bmax || (smx[q] == bmax && sbi[q] < bidx)) { bmax = smx[q]; bidx = sbi[q]; }
      }
      ws->amax[bc] = bidx; ws->vsum[bc] = vs; ws->S0[bc] = s0;
      ws->Sx[bc] = sx; ws->Sy[bc] = sy; ws->Sq2[bc] = sq2;
    }
  } else {
    // ================= role B: per-voxel channel top-2 ====================
    const int sblk = r - fA1;                     // 0..107
    const float4* __restrict__ p =
        reinterpret_cast<const float4*>(f + (size_t)b * NC * XYZ) + (sblk * 256 + t);
    float m1x=-FLT_MAX, m1y=-FLT_MAX, m1z=-FLT_MAX, m1w=-FLT_MAX;
    float m2x=-FLT_MAX, m2y=-FLT_MAX, m2z=-FLT_MAX, m2w=-FLT_MAX;
    float4 s0 = make_float4(0.f, 0.f, 0.f, 0.f);
#pragma unroll 8
    for (int c = 0; c < NC; ++c) {
      const float4 v = p[(size_t)c * Q];
      s0.x = fmaf(v.x, v.x, s0.x);
      s0.y = fmaf(v.y, v.y, s0.y);
      s0.z = fmaf(v.z, v.z, s0.z);
      s0.w = fmaf(v.w, v.w, s0.w);
      TOP2(m1x, m2x, v.x);
      TOP2(m1y, m2y, v.y);
      TOP2(m1z, m2z, v.z);
      TOP2(m1w, m2w, v.w);
    }
    float A = 0.f, Bv = 0.f;
    {
      float q1, rest;
      q1 = m1x*m1x; rest = s0.x - q1;
      A = fmaf(q1, rest, A); A = fmaf(m2x*m2x, q1, A);
      Bv = fmaf(m1x, rest, Bv); Bv = fmaf(m2x, q1, Bv);
      q1 = m1y*m1y; rest = s0.y - q1;
      A = fmaf(q1, rest, A); A = fmaf(m2y*m2y, q1, A);
      Bv = fmaf(m1y, rest, Bv); Bv = fmaf(m2y, q1, Bv);
      q1 = m1z*m1z; rest = s0.z - q1;
      A = fmaf(q1, rest, A); A = fmaf(m2z*m2z, q1, A);
      Bv = fmaf(m1z, rest, Bv); Bv = fmaf(m2z, q1, Bv);
      q1 = m1w*m1w; rest = s0.w - q1;
      A = fmaf(q1, rest, A); A = fmaf(m2w*m2w, q1, A);
      Bv = fmaf(m1w, rest, Bv); Bv = fmaf(m2w, q1, Bv);
    }
    for (int off = 32; off > 0; off >>= 1) {
      A  += __shfl_down(A,  off);
      Bv += __shfl_down(Bv, off);
    }
    __shared__ float rA[4], rB[4];
    if (l == 0) { rA[w] = A; rB[w] = Bv; }
    __syncthreads();
    if (t == 0) {
      const int pidx = b * NBLK_B + sblk;
      ws->pA[pidx] = (rA[0] + rA[1]) + (rA[2] + rA[3]);
      ws->pB[pidx] = (rB[0] + rB[1]) + (rB[2] + rB[3]);
    }
  }
}

// ---------------- Finalize: assemble both scalars in f64 -------------------
__global__ __launch_bounds__(512) void k_fin(const Ws* __restrict__ ws,
                                             float* __restrict__ out) {
  const int t = threadIdx.x;
  double dis, vs, c0, a = 0.0, bb = 0.0;
  {
    const int idx = ws->amax[t];
    const double mx = (double)(idx / YZ);
    const double my = (double)((idx / NZ) % NY);
    const double mz = (double)(idx % NZ);
    const double S0 = ws->S0[t], Sx = ws->Sx[t], Sy = ws->Sy[t], Sq2 = ws->Sq2[t];
    dis = Sq2 - 2.0*mx*Sx - 2.0*my*Sy + (mx*mx + my*my)*S0
        + 2304.0 * (48.0*mz*mz - 2256.0*mz + 35720.0);
    vs = ws->vsum[t];
    c0 = S0;
  }
  for (int i = t; i < K2_BLOCKS; i += 512) { a += ws->pA[i]; bb += ws->pB[i]; }

  for (int off = 32; off > 0; off >>= 1) {
    dis += __shfl_down(dis, off);
    vs  += __shfl_down(vs,  off);
    c0  += __shfl_down(c0,  off);
    a   += __shfl_down(a,   off);
    bb  += __shfl_down(bb,  off);
  }
  __shared__ double sd[8][5];
  const int wid = t >> 6;
  if ((t & 63) == 0) { sd[wid][0]=dis; sd[wid][1]=vs; sd[wid][2]=c0; sd[wid][3]=a; sd[wid][4]=bb; }
  __syncthreads();
  if (t == 0) {
    for (int q = 1; q < 8; ++q) {
      dis += sd[q][0]; vs += sd[q][1]; c0 += sd[q][2]; a += sd[q][3]; bb += sd[q][4];
    }
    const double mgr = vs / SUM_NUM;
    out[0] = (float)(dis / SUM_NUM);
    out[1] = (float)((a - 2.0*mgr*bb + mgr*mgr*c0) / SUM_NUM);
  }
}

extern "C" void kernel_launch(void* const* d_in, const int* in_sizes, int n_in,
                              void* d_out, int out_size, void* d_ws, size_t ws_size,
                              hipStream_t stream) {
  const float* f = (const float*)d_in[0];
  Ws* ws = (Ws*)d_ws;
  float* out = (float*)d_out;
  hipLaunchKernelGGL(k_all, dim3(GRID), dim3(256), 0, stream, f, ws);
  hipLaunchKernelGGL(k_fin, dim3(1),    dim3(512), 0, stream, ws, out);
}